// Round 6
// baseline (223.130 us; speedup 1.0000x reference)
//
#include <hip/hip_runtime.h>
#include <hip/hip_bf16.h>

#define DIM 128
#define NN 40000
#define NE 640000
#define NBLK ((NN + 255) / 256)   // 157

// gfx950 bf16 MFMA fragment types (learn_hip m89/m93/m97):
typedef __attribute__((ext_vector_type(8))) short s16x8;   // 8 bf16 in 4 VGPRs
typedef __attribute__((ext_vector_type(4))) float f32x4;
typedef __attribute__((ext_vector_type(4))) unsigned short u16x4;
typedef __attribute__((ext_vector_type(4))) unsigned int u32x4;

__device__ __forceinline__ float bf16_lo(unsigned v) { return __uint_as_float(v << 16); }
__device__ __forceinline__ float bf16_hi(unsigned v) { return __uint_as_float(v & 0xffff0000u); }
__device__ __forceinline__ unsigned short f_to_bf16(float f) {
    unsigned u = __float_as_uint(f);
    u += 0x7fffu + ((u >> 16) & 1u);   // round-to-nearest-even
    return (unsigned short)(u >> 16);
}

__global__ void fill_const_f32(float* __restrict__ out, int n, float v) {
    int i = blockIdx.x * blockDim.x + threadIdx.x;
    if (i < n) out[i] = v;
}

// ---- fused: fp32->bf16 cvt (x + weights) + degree count + fmt detect ----
// v6: count_deg folded in (deg pre-zeroed by hipMemsetAsync).
// blocks 0..4999: x (4 elems/thread); 5000..5063: weights;
// 5064..7563: degree count (256 edges/block) with PER-BLOCK fmt detect
// (avoids cross-block race on the global flag); block 5064 publishes *flag
// for the later fill_csr kernel.
__global__ void cvt_all(const float* __restrict__ x, unsigned short* __restrict__ xb,
                        const float* __restrict__ w0, const float* __restrict__ w1,
                        const float* __restrict__ w2, const float* __restrict__ w3,
                        unsigned short* __restrict__ wb,
                        int* __restrict__ deg, const int* __restrict__ ei,
                        int* __restrict__ flag) {
    __shared__ int sfmt;
    int b = blockIdx.x;
    if (b >= 5064) {
        // degree-count block
        if (threadIdx.x < 64) {
            // int64 passthrough: odd words (high halves, values < 40000) all zero
            int w = ei[2 * threadIdx.x + 1];
            unsigned long long m = __ballot(w == 0);
            if (threadIdx.x == 0) sfmt = (m == ~0ull) ? 1 : 0;   // 1 = int64
        }
        __syncthreads();
        int f = sfmt;
        if (b == 5064 && threadIdx.x == 0) *flag = f;
        int e = (b - 5064) * 256 + threadIdx.x;
        if (e < NE) {
            int dst = f ? ((const int2*)ei)[NE + e].x : ei[NE + e];
            if ((unsigned)dst < (unsigned)NN) atomicAdd(&deg[dst], 1);
        }
        return;
    }
    const float* src;
    unsigned short* dst;
    size_t i;
    if (b < 5000) {
        src = x; dst = xb;
        i = (size_t)b * 256 + threadIdx.x;           // 1,280,000 f32x4 groups
    } else {
        int w = b - 5000;
        int m = w >> 4;                               // matrix 0..3
        src = (m == 0) ? w0 : (m == 1) ? w1 : (m == 2) ? w2 : w3;
        dst = wb + (size_t)m * 16384;
        i = (size_t)(w & 15) * 256 + threadIdx.x;     // 4096 groups per matrix
    }
    f32x4 v = *(const f32x4*)(src + 4 * i);
    u16x4 o;
    o.x = f_to_bf16(v.x); o.y = f_to_bf16(v.y);
    o.z = f_to_bf16(v.z); o.w = f_to_bf16(v.w);
    *(u16x4*)(dst + 4 * i) = o;
}

// ---------------- CSR build ----------------

__global__ void block_sums(const int* __restrict__ deg, int* __restrict__ bsum) {
    __shared__ int sh[256];
    int i = blockIdx.x * 256 + threadIdx.x;
    sh[threadIdx.x] = (i < NN) ? deg[i] : 0;
    __syncthreads();
    for (int off = 128; off > 0; off >>= 1) {
        if (threadIdx.x < off) sh[threadIdx.x] += sh[threadIdx.x + off];
        __syncthreads();
    }
    if (threadIdx.x == 0) bsum[blockIdx.x] = sh[0];
}

// merged scan: each block redundantly LDS-scans the 157 block sums (8 steps,
// no serial tail) to get its base, then local-scans its 256 deg entries.
__global__ void scan_block2(const int* __restrict__ deg, const int* __restrict__ bsum,
                            int* __restrict__ row_ptr, int* __restrict__ cursor) {
    __shared__ int sh[256];
    int t = threadIdx.x, bid = blockIdx.x;

    int v0 = (t < NBLK) ? bsum[t] : 0;
    sh[t] = v0;
    __syncthreads();
    for (int off = 1; off < 256; off <<= 1) {
        int u = (t >= off) ? sh[t - off] : 0;
        __syncthreads();
        sh[t] += u;
        __syncthreads();
    }
    int base = sh[bid] - bsum[bid];   // exclusive prefix of earlier chunks
    __syncthreads();

    int i = bid * 256 + t;
    int v = (i < NN) ? deg[i] : 0;
    sh[t] = v;
    __syncthreads();
    for (int off = 1; off < 256; off <<= 1) {
        int u = (t >= off) ? sh[t - off] : 0;
        __syncthreads();
        sh[t] += u;
        __syncthreads();
    }
    int excl = sh[t] - v + base;
    if (i < NN) { row_ptr[i] = excl; cursor[i] = excl; }
    if (i == NN - 1) row_ptr[NN] = excl + v;
}

// v6: 4 edges per thread (strided) -> 4 independent load/atomic/store chains.
__global__ void fill_csr(const int* __restrict__ ei, const int* __restrict__ fmt,
                         int* __restrict__ cursor, int* __restrict__ sorted_src) {
    int gid = blockIdx.x * blockDim.x + threadIdx.x;   // 0..159999
    int f = *fmt;
    int s[4], dd[4];
#pragma unroll
    for (int u = 0; u < 4; ++u) {
        int e = gid + u * 160000;
        if (f) {
            s[u]  = ((const int2*)ei)[e].x;
            dd[u] = ((const int2*)ei)[NE + e].x;
        } else {
            s[u]  = ei[e];
            dd[u] = ei[NE + e];
        }
    }
#pragma unroll
    for (int u = 0; u < 4; ++u) {
        if ((unsigned)dd[u] < (unsigned)NN) {
            int pos = atomicAdd(&cursor[dd[u]], 1);
            if ((unsigned)pos < (unsigned)NE) sorted_src[pos] = s[u];
        }
    }
}

// ---------------- fused layer: aggregate(64 nodes) -> LDS frag layout -> GEMM ----
// v6 (fixed): fully software-pipelined gather stream. r4 proved chain
// shortening is the lever (-21us); v6 removes the remaining serial epochs:
//  - ALL window idx loads (up to 3 per node x 2 nodes, 16 edges/window,
//    covers deg<=48) issue once at group start, coalesced + clamped.
//  - Edges stream through ping-pong 8-gather register buffers U_/V_
//    (statically indexed): sub-batch k+1's 8 loads are in flight while
//    sub-batch k accumulates.  All batches clamp+weight (r4-proven, exact).
//  - deg>48: clamped 16-burst tail loop, r4-style.
// NOTE (r5 compile fail): macro weight param must NOT be named `w` — the
// preprocessor substitutes it inside the member access `(v).w`. Named `W` now.
// LDS frag layout + XOR swizzle unchanged from v4.

#define ACC8W(A, v, W)                                         \
    A[0] = fmaf(W, bf16_lo((v).x), A[0]);                      \
    A[1] = fmaf(W, bf16_hi((v).x), A[1]);                      \
    A[2] = fmaf(W, bf16_lo((v).y), A[2]);                      \
    A[3] = fmaf(W, bf16_hi((v).y), A[3]);                      \
    A[4] = fmaf(W, bf16_lo((v).z), A[4]);                      \
    A[5] = fmaf(W, bf16_hi((v).z), A[5]);                      \
    A[6] = fmaf(W, bf16_lo((v).w), A[6]);                      \
    A[7] = fmaf(W, bf16_hi((v).w), A[7]);

// one clamped gather: edge EE of a node with degree D (DM1=D-1), window idx
// regs I0/I1/I2 (16 edges each).  Uses enclosing-scope gbase/lid/xin.
#define GL1(DST, EE, D, DM1, I0, I1, I2)                               \
    {                                                                   \
        int ce_ = ((EE) < (D)) ? (EE) : (DM1);                          \
        int ix_ = (ce_ >= 32) ? (I2) : ((ce_ >= 16) ? (I1) : (I0));     \
        int s_ = __shfl(ix_, gbase + (ce_ & 15));                       \
        DST = *(const u32x4*)(xin + (size_t)s_ * DIM + lid * 8);        \
    }

#define GLOAD8(B, E0, D, DM1, I0, I1, I2)        \
    GL1(B[0], (E0) + 0, D, DM1, I0, I1, I2)      \
    GL1(B[1], (E0) + 1, D, DM1, I0, I1, I2)      \
    GL1(B[2], (E0) + 2, D, DM1, I0, I1, I2)      \
    GL1(B[3], (E0) + 3, D, DM1, I0, I1, I2)      \
    GL1(B[4], (E0) + 4, D, DM1, I0, I1, I2)      \
    GL1(B[5], (E0) + 5, D, DM1, I0, I1, I2)      \
    GL1(B[6], (E0) + 6, D, DM1, I0, I1, I2)      \
    GL1(B[7], (E0) + 7, D, DM1, I0, I1, I2)

#define GA1(AA, BK, EE, D)                                  \
    { float wt_ = ((EE) < (D)) ? 1.f : 0.f; ACC8W(AA, BK, wt_); }

#define GACC8(AA, BB, B, E0, D)       \
    GA1(AA, B[0], (E0) + 0, D)        \
    GA1(BB, B[1], (E0) + 1, D)        \
    GA1(AA, B[2], (E0) + 2, D)        \
    GA1(BB, B[3], (E0) + 3, D)        \
    GA1(AA, B[4], (E0) + 4, D)        \
    GA1(BB, B[5], (E0) + 5, D)        \
    GA1(AA, B[6], (E0) + 6, D)        \
    GA1(BB, B[7], (E0) + 7, D)

// rare tail (>48 edges): clamped 16-burst using a fresh idx load
#define GLT1(DST, K)                                                    \
    {   int cj_ = ((K) < rem_) ? (K) : rm1_;                            \
        int s_ = __shfl(idx_, gbase + cj_);                             \
        DST = *(const u32x4*)(xin + (size_t)s_ * DIM + lid * 8); }
#define GAT1(AA, BK, K)                                                 \
    {   float wt_ = ((K) < rem_) ? 1.f : 0.f; ACC8W(AA, BK, wt_); }

// full node stream: ping-pong U_/V_ sub-batches of 8 over the <=48 region,
// then the rare tail.  AA/BB are the two fp32 accumulator chains.
#define NODE_STREAM(AA, BB, ST, EN, D, I0, I1, I2)                       \
    if ((D) > 0) {                                                        \
        int dm1_ = (D) - 1;                                               \
        int ds_ = ((D) < 48) ? (D) : 48;                                  \
        GLOAD8(U_, 0, D, dm1_, I0, I1, I2)                                \
        if (ds_ > 8)  { GLOAD8(V_, 8, D, dm1_, I0, I1, I2) }              \
        GACC8(AA, BB, U_, 0, D)                                           \
        if (ds_ > 16) { GLOAD8(U_, 16, D, dm1_, I0, I1, I2) }             \
        if (ds_ > 8)  { GACC8(AA, BB, V_, 8, D) }                         \
        if (ds_ > 24) { GLOAD8(V_, 24, D, dm1_, I0, I1, I2) }             \
        if (ds_ > 16) { GACC8(AA, BB, U_, 16, D) }                        \
        if (ds_ > 32) { GLOAD8(U_, 32, D, dm1_, I0, I1, I2) }             \
        if (ds_ > 24) { GACC8(AA, BB, V_, 24, D) }                        \
        if (ds_ > 40) { GLOAD8(V_, 40, D, dm1_, I0, I1, I2) }             \
        if (ds_ > 32) { GACC8(AA, BB, U_, 32, D) }                        \
        if (ds_ > 40) { GACC8(AA, BB, V_, 40, D) }                        \
        for (int ii_ = (ST) + 48; ii_ < (EN); ii_ += 16) {                \
            int rem_ = (EN) - ii_;  if (rem_ > 16) rem_ = 16;             \
            int rm1_ = rem_ - 1;                                          \
            int idx_ = sorted_src[ii_ + ((lid < rem_) ? lid : rm1_)];     \
            GLT1(U_[0], 0) GLT1(U_[1], 1) GLT1(U_[2], 2) GLT1(U_[3], 3)   \
            GLT1(U_[4], 4) GLT1(U_[5], 5) GLT1(U_[6], 6) GLT1(U_[7], 7)   \
            GLT1(V_[0], 8) GLT1(V_[1], 9) GLT1(V_[2],10) GLT1(V_[3],11)   \
            GLT1(V_[4],12) GLT1(V_[5],13) GLT1(V_[6],14) GLT1(V_[7],15)   \
            GAT1(AA, U_[0], 0) GAT1(BB, U_[1], 1)                         \
            GAT1(AA, U_[2], 2) GAT1(BB, U_[3], 3)                         \
            GAT1(AA, U_[4], 4) GAT1(BB, U_[5], 5)                         \
            GAT1(AA, U_[6], 6) GAT1(BB, U_[7], 7)                         \
            GAT1(AA, V_[0], 8) GAT1(BB, V_[1], 9)                         \
            GAT1(AA, V_[2],10) GAT1(BB, V_[3],11)                         \
            GAT1(AA, V_[4],12) GAT1(BB, V_[5],13)                         \
            GAT1(AA, V_[6],14) GAT1(BB, V_[7],15)                         \
        }                                                                 \
    }

template <bool WRITE_F32>
__global__ __launch_bounds__(512) void sage_layer(
    const unsigned short* __restrict__ xin,    // gather table / self features
    const int* __restrict__ row_ptr,
    const int* __restrict__ sorted_src,
    const unsigned short* __restrict__ Wl,     // [128,128] bf16
    const unsigned short* __restrict__ Wr,
    const float* __restrict__ bias,            // [128] fp32
    void* __restrict__ outv) {
    __shared__ unsigned short lds_mean[64 * 128];  // 16 KB, swizzled frag layout
    __shared__ unsigned short lds_hs[64 * 128];    // 16 KB, swizzled frag layout

    int tid = threadIdx.x;
    int lane = tid & 63;
    int wv = tid >> 6;                 // 0..7
    int row0 = blockIdx.x * 64;

    // ---- Phase A: stage hself rows (coalesced global read, swizzled LDS write) ----
    {
        int r = tid >> 3;                      // row-in-block 0..63
        int lid0 = (tid & 7) * 2;              // 16B chunk 0,2,..,14
        int lid1 = lid0 + 1;
        const unsigned short* src = xin + (size_t)(row0 + r) * DIM + lid0 * 8;
        u32x4 v0 = *(const u32x4*)(src);
        u32x4 v1 = *(const u32x4*)(src + 8);
        int base = (r >> 4) * 2048;
        int o0 = base + (lid0 >> 2) * 512 + (lid0 & 3) * 128 + (((r & 15) ^ lid0) * 8);
        int o1 = base + (lid1 >> 2) * 512 + (lid1 & 3) * 128 + (((r & 15) ^ lid1) * 8);
        *(u32x4*)(lds_hs + o0) = v0;
        *(u32x4*)(lds_hs + o1) = v1;
    }

    // ---- Phase B: aggregate 2 nodes per 16-lane group (32 groups) ----
    {
        int grp = lane >> 4;
        int lid = lane & 15;
        int gbase = grp << 4;
        int g = wv * 4 + grp;                  // group id 0..31

        int n0 = row0 + g, n1 = row0 + 32 + g;
        int st0 = row_ptr[n0], en0 = row_ptr[n0 + 1];
        int st1 = row_ptr[n1], en1 = row_ptr[n1 + 1];
        int d0 = en0 - st0, d1 = en1 - st1;

        // upfront: all window idx loads for BOTH nodes (coalesced, clamped)
        int i0 = 0, i1 = 0, i2 = 0, j0 = 0, j1 = 0, j2 = 0;
        if (d0 > 0) {
            int dm = d0 - 1;
            i0 = sorted_src[st0 + ((lid      < d0) ? lid      : dm)];
            i1 = sorted_src[st0 + ((16 + lid < d0) ? 16 + lid : dm)];
            i2 = sorted_src[st0 + ((32 + lid < d0) ? 32 + lid : dm)];
        }
        if (d1 > 0) {
            int dm = d1 - 1;
            j0 = sorted_src[st1 + ((lid      < d1) ? lid      : dm)];
            j1 = sorted_src[st1 + ((16 + lid < d1) ? 16 + lid : dm)];
            j2 = sorted_src[st1 + ((32 + lid < d1) ? 32 + lid : dm)];
        }

        u32x4 U_[8], V_[8];
        float a[8] = {0.f, 0.f, 0.f, 0.f, 0.f, 0.f, 0.f, 0.f};
        float b[8] = {0.f, 0.f, 0.f, 0.f, 0.f, 0.f, 0.f, 0.f};

        // node 0
        NODE_STREAM(a, b, st0, en0, d0, i0, i1, i2)
        {
            float inv = 1.f / (float)(d0 > 1 ? d0 : 1);
            u32x4 o;
            o.x = (unsigned)f_to_bf16((a[0] + b[0]) * inv) | ((unsigned)f_to_bf16((a[1] + b[1]) * inv) << 16);
            o.y = (unsigned)f_to_bf16((a[2] + b[2]) * inv) | ((unsigned)f_to_bf16((a[3] + b[3]) * inv) << 16);
            o.z = (unsigned)f_to_bf16((a[4] + b[4]) * inv) | ((unsigned)f_to_bf16((a[5] + b[5]) * inv) << 16);
            o.w = (unsigned)f_to_bf16((a[6] + b[6]) * inv) | ((unsigned)f_to_bf16((a[7] + b[7]) * inv) << 16);
            int nb = g;
            int off = (nb >> 4) * 2048 + (lid >> 2) * 512 + (lid & 3) * 128
                    + (((nb & 15) ^ lid) * 8);
            *(u32x4*)(lds_mean + off) = o;
        }

#pragma unroll
        for (int k = 0; k < 8; ++k) { a[k] = 0.f; b[k] = 0.f; }

        // node 1
        NODE_STREAM(a, b, st1, en1, d1, j0, j1, j2)
        {
            float inv = 1.f / (float)(d1 > 1 ? d1 : 1);
            u32x4 o;
            o.x = (unsigned)f_to_bf16((a[0] + b[0]) * inv) | ((unsigned)f_to_bf16((a[1] + b[1]) * inv) << 16);
            o.y = (unsigned)f_to_bf16((a[2] + b[2]) * inv) | ((unsigned)f_to_bf16((a[3] + b[3]) * inv) << 16);
            o.z = (unsigned)f_to_bf16((a[4] + b[4]) * inv) | ((unsigned)f_to_bf16((a[5] + b[5]) * inv) << 16);
            o.w = (unsigned)f_to_bf16((a[6] + b[6]) * inv) | ((unsigned)f_to_bf16((a[7] + b[7]) * inv) << 16);
            int nb = 32 + g;
            int off = (nb >> 4) * 2048 + (lid >> 2) * 512 + (lid & 3) * 128
                    + (((nb & 15) ^ lid) * 8);
            *(u32x4*)(lds_mean + off) = o;
        }
    }

    __syncthreads();

    // ---- Phase C: GEMM. 8 waves x (64 rows x 16 cols) covers 64x128 ----
    {
        int quad = lane >> 4;
        int m16 = lane & 15;
        int bcol = wv * 16 + m16;              // 0..127
        const unsigned short* wl0 = Wl + (size_t)bcol * DIM + quad * 8;
        const unsigned short* wr0 = Wr + (size_t)bcol * DIM + quad * 8;
        s16x8 bl[4], br[4];
#pragma unroll
        for (int kb = 0; kb < 4; ++kb) {
            bl[kb] = *(const s16x8*)(wl0 + kb * 32);
            br[kb] = *(const s16x8*)(wr0 + kb * 32);
        }
        f32x4 acc[4] = {{0,0,0,0},{0,0,0,0},{0,0,0,0},{0,0,0,0}};
#pragma unroll
        for (int t = 0; t < 4; ++t) {
#pragma unroll
            for (int kb = 0; kb < 4; ++kb) {
                int lo = (lane ^ ((kb << 2) | quad)) << 3;
                s16x8 am = *(const s16x8*)(lds_mean + t * 2048 + kb * 512 + lo);
                acc[t] = __builtin_amdgcn_mfma_f32_16x16x32_bf16(am, bl[kb], acc[t], 0, 0, 0);
            }
#pragma unroll
            for (int kb = 0; kb < 4; ++kb) {
                int lo = (lane ^ ((kb << 2) | quad)) << 3;
                s16x8 ah = *(const s16x8*)(lds_hs + t * 2048 + kb * 512 + lo);
                acc[t] = __builtin_amdgcn_mfma_f32_16x16x32_bf16(ah, br[kb], acc[t], 0, 0, 0);
            }
        }
        float bv = bias[bcol];
#pragma unroll
        for (int t = 0; t < 4; ++t) {
#pragma unroll
            for (int r = 0; r < 4; ++r) {
                int orow = row0 + t * 16 + quad * 4 + r;
                float v = fmaxf(acc[t][r] + bv, 0.f);   // relu
                if (WRITE_F32)
                    ((float*)outv)[(size_t)orow * DIM + bcol] = v;
                else
                    ((unsigned short*)outv)[(size_t)orow * DIM + bcol] = f_to_bf16(v);
            }
        }
    }
}

// ---------------- launch ----------------

extern "C" void kernel_launch(void* const* d_in, const int* in_sizes, int n_in,
                              void* d_out, int out_size, void* d_ws, size_t ws_size,
                              hipStream_t stream) {
    const float* x   = (const float*)d_in[0];
    const int*   ei  = (const int*)d_in[1];
    const float* W1l = (const float*)d_in[2];
    const float* b1l = (const float*)d_in[3];
    const float* W1r = (const float*)d_in[4];
    const float* W2l = (const float*)d_in[5];
    const float* b2l = (const float*)d_in[6];
    const float* W2r = (const float*)d_in[7];
    float* out = (float*)d_out;

    const int OUT_ELEMS = NN * DIM;        // 5,120,000

    // workspace layout (256B-aligned)
    const size_t OFF_DEG  = 0;             // N ints
    const size_t OFF_ROW  = 163840;        // N+1 ints
    const size_t OFF_BSUM = 324608;        // NBLK ints (in ROW region slack)
    const size_t OFF_CUR  = 327680;        // N ints
    const size_t OFF_FMT  = 491264;        // 1 int
    const size_t OFF_SRT  = 491520;        // E ints
    const size_t OFF_WB   = 3051520;       // 4 * 16384 bf16
    const size_t OFF_XB   = 3182592;       // N*128 bf16
    const size_t OFF_H1   = 23662592;      // N*128 bf16 (MEAN slot unused)
    const size_t NEEDED   = 33902592;

    if (ws_size < NEEDED) {
        fill_const_f32<<<(OUT_ELEMS + 255) / 256, 256, 0, stream>>>(out, OUT_ELEMS, 50.0f);
        return;
    }

    char* ws = (char*)d_ws;
    int* deg     = (int*)(ws + OFF_DEG);
    int* row_ptr = (int*)(ws + OFF_ROW);
    int* bsum    = (int*)(ws + OFF_BSUM);
    int* cursor  = (int*)(ws + OFF_CUR);
    int* fmtflag = (int*)(ws + OFF_FMT);
    int* sorted  = (int*)(ws + OFF_SRT);
    unsigned short* Wb    = (unsigned short*)(ws + OFF_WB);
    unsigned short* xb    = (unsigned short*)(ws + OFF_XB);
    unsigned short* h1b   = (unsigned short*)(ws + OFF_H1);
    unsigned short* W1lb = Wb;
    unsigned short* W1rb = Wb + 16384;
    unsigned short* W2lb = Wb + 32768;
    unsigned short* W2rb = Wb + 49152;

    // 0: zero degree array (graph-capturable memset)
    hipMemsetAsync(deg, 0, NN * sizeof(int), stream);
    // 1: conversions + degree count + fmt detect (fused)
    cvt_all<<<7564, 256, 0, stream>>>(x, xb, W1l, W1r, W2l, W2r, Wb, deg, ei, fmtflag);
    // 2-4: CSR build
    block_sums<<<NBLK, 256, 0, stream>>>(deg, bsum);
    scan_block2<<<NBLK, 256, 0, stream>>>(deg, bsum, row_ptr, cursor);
    fill_csr<<<625, 256, 0, stream>>>(ei, fmtflag, cursor, sorted);

    // 5: layer 1 (fused aggregate+GEMM, 8 waves/block)
    sage_layer<false><<<NN / 64, 512, 0, stream>>>(xb, row_ptr, sorted, W1lb, W1rb, b1l, h1b);
    // 6: layer 2 (fused aggregate+GEMM, 8 waves/block)
    sage_layer<true><<<NN / 64, 512, 0, stream>>>(h1b, row_ptr, sorted, W2lb, W2rb, b2l, out);
}

// Round 7
// 209.593 us; speedup vs baseline: 1.0646x; 1.0646x over previous
//
#include <hip/hip_runtime.h>
#include <hip/hip_bf16.h>

#define DIM 128
#define NN 40000
#define NE 640000
#define NBLK ((NN + 255) / 256)   // 157

// gfx950 bf16 MFMA fragment types (learn_hip m89/m93/m97):
typedef __attribute__((ext_vector_type(8))) short s16x8;   // 8 bf16 in 4 VGPRs
typedef __attribute__((ext_vector_type(4))) float f32x4;
typedef __attribute__((ext_vector_type(4))) unsigned short u16x4;
typedef __attribute__((ext_vector_type(4))) unsigned int u32x4;

__device__ __forceinline__ float bf16_lo(unsigned v) { return __uint_as_float(v << 16); }
__device__ __forceinline__ float bf16_hi(unsigned v) { return __uint_as_float(v & 0xffff0000u); }
__device__ __forceinline__ unsigned short f_to_bf16(float f) {
    unsigned u = __float_as_uint(f);
    u += 0x7fffu + ((u >> 16) & 1u);   // round-to-nearest-even
    return (unsigned short)(u >> 16);
}

__global__ void fill_const_f32(float* __restrict__ out, int n, float v) {
    int i = blockIdx.x * blockDim.x + threadIdx.x;
    if (i < n) out[i] = v;
}

// ---- fused: fp32->bf16 cvt (x + weights) + degree count + fmt detect ----
// (r6-proven correct) blocks 0..4999: x; 5000..5063: weights;
// 5064..7563: degree count (256 edges/block) with PER-BLOCK fmt detect;
// block 5064 publishes *flag for fill_csr.
__global__ void cvt_all(const float* __restrict__ x, unsigned short* __restrict__ xb,
                        const float* __restrict__ w0, const float* __restrict__ w1,
                        const float* __restrict__ w2, const float* __restrict__ w3,
                        unsigned short* __restrict__ wb,
                        int* __restrict__ deg, const int* __restrict__ ei,
                        int* __restrict__ flag) {
    __shared__ int sfmt;
    int b = blockIdx.x;
    if (b >= 5064) {
        // degree-count block
        if (threadIdx.x < 64) {
            // int64 passthrough: odd words (high halves, values < 40000) all zero
            int w = ei[2 * threadIdx.x + 1];
            unsigned long long m = __ballot(w == 0);
            if (threadIdx.x == 0) sfmt = (m == ~0ull) ? 1 : 0;   // 1 = int64
        }
        __syncthreads();
        int f = sfmt;
        if (b == 5064 && threadIdx.x == 0) *flag = f;
        int e = (b - 5064) * 256 + threadIdx.x;
        if (e < NE) {
            int dst = f ? ((const int2*)ei)[NE + e].x : ei[NE + e];
            if ((unsigned)dst < (unsigned)NN) atomicAdd(&deg[dst], 1);
        }
        return;
    }
    const float* src;
    unsigned short* dst;
    size_t i;
    if (b < 5000) {
        src = x; dst = xb;
        i = (size_t)b * 256 + threadIdx.x;           // 1,280,000 f32x4 groups
    } else {
        int w = b - 5000;
        int m = w >> 4;                               // matrix 0..3
        src = (m == 0) ? w0 : (m == 1) ? w1 : (m == 2) ? w2 : w3;
        dst = wb + (size_t)m * 16384;
        i = (size_t)(w & 15) * 256 + threadIdx.x;     // 4096 groups per matrix
    }
    f32x4 v = *(const f32x4*)(src + 4 * i);
    u16x4 o;
    o.x = f_to_bf16(v.x); o.y = f_to_bf16(v.y);
    o.z = f_to_bf16(v.z); o.w = f_to_bf16(v.w);
    *(u16x4*)(dst + 4 * i) = o;
}

// ---------------- CSR build ----------------

__global__ void block_sums(const int* __restrict__ deg, int* __restrict__ bsum) {
    __shared__ int sh[256];
    int i = blockIdx.x * 256 + threadIdx.x;
    sh[threadIdx.x] = (i < NN) ? deg[i] : 0;
    __syncthreads();
    for (int off = 128; off > 0; off >>= 1) {
        if (threadIdx.x < off) sh[threadIdx.x] += sh[threadIdx.x + off];
        __syncthreads();
    }
    if (threadIdx.x == 0) bsum[blockIdx.x] = sh[0];
}

// merged scan: each block redundantly LDS-scans the 157 block sums (8 steps,
// no serial tail) to get its base, then local-scans its 256 deg entries.
__global__ void scan_block2(const int* __restrict__ deg, const int* __restrict__ bsum,
                            int* __restrict__ row_ptr, int* __restrict__ cursor) {
    __shared__ int sh[256];
    int t = threadIdx.x, bid = blockIdx.x;

    int v0 = (t < NBLK) ? bsum[t] : 0;
    sh[t] = v0;
    __syncthreads();
    for (int off = 1; off < 256; off <<= 1) {
        int u = (t >= off) ? sh[t - off] : 0;
        __syncthreads();
        sh[t] += u;
        __syncthreads();
    }
    int base = sh[bid] - bsum[bid];   // exclusive prefix of earlier chunks
    __syncthreads();

    int i = bid * 256 + t;
    int v = (i < NN) ? deg[i] : 0;
    sh[t] = v;
    __syncthreads();
    for (int off = 1; off < 256; off <<= 1) {
        int u = (t >= off) ? sh[t - off] : 0;
        __syncthreads();
        sh[t] += u;
        __syncthreads();
    }
    int excl = sh[t] - v + base;
    if (i < NN) { row_ptr[i] = excl; cursor[i] = excl; }
    if (i == NN - 1) row_ptr[NN] = excl + v;
}

// 4 edges per thread (strided) -> 4 independent load/atomic/store chains.
__global__ void fill_csr(const int* __restrict__ ei, const int* __restrict__ fmt,
                         int* __restrict__ cursor, int* __restrict__ sorted_src) {
    int gid = blockIdx.x * blockDim.x + threadIdx.x;   // 0..159999
    int f = *fmt;
    int s[4], dd[4];
#pragma unroll
    for (int u = 0; u < 4; ++u) {
        int e = gid + u * 160000;
        if (f) {
            s[u]  = ((const int2*)ei)[e].x;
            dd[u] = ((const int2*)ei)[NE + e].x;
        } else {
            s[u]  = ei[e];
            dd[u] = ei[NE + e];
        }
    }
#pragma unroll
    for (int u = 0; u < 4; ++u) {
        if ((unsigned)dd[u] < (unsigned)NN) {
            int pos = atomicAdd(&cursor[dd[u]], 1);
            if ((unsigned)pos < (unsigned)NE) sorted_src[pos] = s[u];
        }
    }
}

// ---------------- fused layer: aggregate(64 nodes) -> LDS frag layout -> GEMM ----
// v7 = r4-proven v5 body (REVERT of v6: the pipelined macro stream cost +15us
// from register pressure [U_/V_ = 64 VGPRs] + per-edge clamp VALU overhead).
// v5: main loop in 16-edge coalesced batches, 4-deep gather bursts; remainder
// branch-free clamped bursts of 8 with weight-0 padding (exact).
// LDS frag layout + XOR swizzle unchanged from v4.

#define ACC8(A, v)                                 \
    A[0] += bf16_lo((v).x); A[1] += bf16_hi((v).x); \
    A[2] += bf16_lo((v).y); A[3] += bf16_hi((v).y); \
    A[4] += bf16_lo((v).z); A[5] += bf16_hi((v).z); \
    A[6] += bf16_lo((v).w); A[7] += bf16_hi((v).w);

// NOTE: weight param named W (never `w`) — macro substitution would hit (v).w.
#define ACC8W(A, v, W)                                         \
    A[0] = fmaf(W, bf16_lo((v).x), A[0]);                      \
    A[1] = fmaf(W, bf16_hi((v).x), A[1]);                      \
    A[2] = fmaf(W, bf16_lo((v).y), A[2]);                      \
    A[3] = fmaf(W, bf16_hi((v).y), A[3]);                      \
    A[4] = fmaf(W, bf16_lo((v).z), A[4]);                      \
    A[5] = fmaf(W, bf16_hi((v).z), A[5]);                      \
    A[6] = fmaf(W, bf16_lo((v).w), A[6]);                      \
    A[7] = fmaf(W, bf16_hi((v).w), A[7]);

template <bool WRITE_F32>
__global__ __launch_bounds__(512) void sage_layer(
    const unsigned short* __restrict__ xin,    // gather table / self features
    const int* __restrict__ row_ptr,
    const int* __restrict__ sorted_src,
    const unsigned short* __restrict__ Wl,     // [128,128] bf16
    const unsigned short* __restrict__ Wr,
    const float* __restrict__ bias,            // [128] fp32
    void* __restrict__ outv) {
    __shared__ unsigned short lds_mean[64 * 128];  // 16 KB, swizzled frag layout
    __shared__ unsigned short lds_hs[64 * 128];    // 16 KB, swizzled frag layout

    int tid = threadIdx.x;
    int lane = tid & 63;
    int wv = tid >> 6;                 // 0..7
    int row0 = blockIdx.x * 64;

    // ---- Phase A: stage hself rows (coalesced global read, swizzled LDS write) ----
    {
        int r = tid >> 3;                      // row-in-block 0..63
        int lid0 = (tid & 7) * 2;              // 16B chunk 0,2,..,14
        int lid1 = lid0 + 1;
        const unsigned short* src = xin + (size_t)(row0 + r) * DIM + lid0 * 8;
        u32x4 v0 = *(const u32x4*)(src);
        u32x4 v1 = *(const u32x4*)(src + 8);
        int base = (r >> 4) * 2048;
        int o0 = base + (lid0 >> 2) * 512 + (lid0 & 3) * 128 + (((r & 15) ^ lid0) * 8);
        int o1 = base + (lid1 >> 2) * 512 + (lid1 & 3) * 128 + (((r & 15) ^ lid1) * 8);
        *(u32x4*)(lds_hs + o0) = v0;
        *(u32x4*)(lds_hs + o1) = v1;
    }

    // ---- Phase B: aggregate 2 nodes per 16-lane group (32 groups) ----
    {
        int grp = lane >> 4;
        int lid = lane & 15;
        int gbase = grp << 4;
        int g = wv * 4 + grp;                  // group id 0..31

        // hoist both nodes' row_ptr reads ahead of the gather chains
        int n0 = row0 + g, n1 = row0 + 32 + g;
        int st0 = row_ptr[n0], en0 = row_ptr[n0 + 1];
        int st1 = row_ptr[n1], en1 = row_ptr[n1 + 1];

#pragma unroll
        for (int it = 0; it < 2; ++it) {
            int nb = it * 32 + g;              // node in block
            int start = it ? st1 : st0;
            int end   = it ? en1 : en0;

            float a[8] = {0.f, 0.f, 0.f, 0.f, 0.f, 0.f, 0.f, 0.f};
            float b[8] = {0.f, 0.f, 0.f, 0.f, 0.f, 0.f, 0.f, 0.f};

            int i = start;
            for (; i + 16 <= end; i += 16) {
                int idx = sorted_src[i + lid];
#pragma unroll
                for (int j = 0; j < 16; j += 4) {
                    int s0 = __shfl(idx, gbase + j);
                    int s1 = __shfl(idx, gbase + j + 1);
                    int s2 = __shfl(idx, gbase + j + 2);
                    int s3 = __shfl(idx, gbase + j + 3);
                    u32x4 v0 = *(const u32x4*)(xin + (size_t)s0 * DIM + lid * 8);
                    u32x4 v1 = *(const u32x4*)(xin + (size_t)s1 * DIM + lid * 8);
                    u32x4 v2 = *(const u32x4*)(xin + (size_t)s2 * DIM + lid * 8);
                    u32x4 v3 = *(const u32x4*)(xin + (size_t)s3 * DIM + lid * 8);
                    ACC8(a, v0);
                    ACC8(b, v1);
                    ACC8(a, v2);
                    ACC8(b, v3);
                }
            }
            // remainder (< 16 edges): branch-free clamped bursts of 8.
            // Slots j >= rem load row (rem-1) again (same-address -> L1 hit)
            // and accumulate with weight 0 (exact).
            int rem = end - i;
            if (rem > 0) {
                int src_i = (i + lid < end) ? (i + lid) : (end - 1);
                int idx = sorted_src[src_i];
                int rm1 = rem - 1;
#pragma unroll
                for (int j0 = 0; j0 < 16; j0 += 8) {
                    if (j0 < rem) {
                        u32x4 vv[8];
#pragma unroll
                        for (int k = 0; k < 8; ++k) {
                            int jj = j0 + k;
                            int cj = (jj < rem) ? jj : rm1;
                            int s = __shfl(idx, gbase + cj);
                            vv[k] = *(const u32x4*)(xin + (size_t)s * DIM + lid * 8);
                        }
#pragma unroll
                        for (int k = 0; k < 8; ++k) {
                            float wt = (j0 + k < rem) ? 1.f : 0.f;
                            if (k & 1) { ACC8W(b, vv[k], wt); }
                            else       { ACC8W(a, vv[k], wt); }
                        }
                    }
                }
            }
#pragma unroll
            for (int k = 0; k < 8; ++k) a[k] += b[k];

            int d = end - start;
            float inv = 1.f / (float)(d > 1 ? d : 1);
            u32x4 o;
            o.x = (unsigned)f_to_bf16(a[0] * inv) | ((unsigned)f_to_bf16(a[1] * inv) << 16);
            o.y = (unsigned)f_to_bf16(a[2] * inv) | ((unsigned)f_to_bf16(a[3] * inv) << 16);
            o.z = (unsigned)f_to_bf16(a[4] * inv) | ((unsigned)f_to_bf16(a[5] * inv) << 16);
            o.w = (unsigned)f_to_bf16(a[6] * inv) | ((unsigned)f_to_bf16(a[7] * inv) << 16);
            int off = (nb >> 4) * 2048 + (lid >> 2) * 512 + (lid & 3) * 128
                    + (((nb & 15) ^ lid) * 8);
            *(u32x4*)(lds_mean + off) = o;
        }
    }

    __syncthreads();

    // ---- Phase C: GEMM. 8 waves x (64 rows x 16 cols) covers 64x128 ----
    {
        int quad = lane >> 4;
        int m16 = lane & 15;
        int bcol = wv * 16 + m16;              // 0..127
        const unsigned short* wl0 = Wl + (size_t)bcol * DIM + quad * 8;
        const unsigned short* wr0 = Wr + (size_t)bcol * DIM + quad * 8;
        s16x8 bl[4], br[4];
#pragma unroll
        for (int kb = 0; kb < 4; ++kb) {
            bl[kb] = *(const s16x8*)(wl0 + kb * 32);
            br[kb] = *(const s16x8*)(wr0 + kb * 32);
        }
        f32x4 acc[4] = {{0,0,0,0},{0,0,0,0},{0,0,0,0},{0,0,0,0}};
#pragma unroll
        for (int t = 0; t < 4; ++t) {
#pragma unroll
            for (int kb = 0; kb < 4; ++kb) {
                int lo = (lane ^ ((kb << 2) | quad)) << 3;
                s16x8 am = *(const s16x8*)(lds_mean + t * 2048 + kb * 512 + lo);
                acc[t] = __builtin_amdgcn_mfma_f32_16x16x32_bf16(am, bl[kb], acc[t], 0, 0, 0);
            }
#pragma unroll
            for (int kb = 0; kb < 4; ++kb) {
                int lo = (lane ^ ((kb << 2) | quad)) << 3;
                s16x8 ah = *(const s16x8*)(lds_hs + t * 2048 + kb * 512 + lo);
                acc[t] = __builtin_amdgcn_mfma_f32_16x16x32_bf16(ah, br[kb], acc[t], 0, 0, 0);
            }
        }
        float bv = bias[bcol];
#pragma unroll
        for (int t = 0; t < 4; ++t) {
#pragma unroll
            for (int r = 0; r < 4; ++r) {
                int orow = row0 + t * 16 + quad * 4 + r;
                float v = fmaxf(acc[t][r] + bv, 0.f);   // relu
                if (WRITE_F32)
                    ((float*)outv)[(size_t)orow * DIM + bcol] = v;
                else
                    ((unsigned short*)outv)[(size_t)orow * DIM + bcol] = f_to_bf16(v);
            }
        }
    }
}

// ---------------- launch ----------------

extern "C" void kernel_launch(void* const* d_in, const int* in_sizes, int n_in,
                              void* d_out, int out_size, void* d_ws, size_t ws_size,
                              hipStream_t stream) {
    const float* x   = (const float*)d_in[0];
    const int*   ei  = (const int*)d_in[1];
    const float* W1l = (const float*)d_in[2];
    const float* b1l = (const float*)d_in[3];
    const float* W1r = (const float*)d_in[4];
    const float* W2l = (const float*)d_in[5];
    const float* b2l = (const float*)d_in[6];
    const float* W2r = (const float*)d_in[7];
    float* out = (float*)d_out;

    const int OUT_ELEMS = NN * DIM;        // 5,120,000

    // workspace layout (256B-aligned)
    const size_t OFF_DEG  = 0;             // N ints
    const size_t OFF_ROW  = 163840;        // N+1 ints
    const size_t OFF_BSUM = 324608;        // NBLK ints (in ROW region slack)
    const size_t OFF_CUR  = 327680;        // N ints
    const size_t OFF_FMT  = 491264;        // 1 int
    const size_t OFF_SRT  = 491520;        // E ints
    const size_t OFF_WB   = 3051520;       // 4 * 16384 bf16
    const size_t OFF_XB   = 3182592;       // N*128 bf16
    const size_t OFF_H1   = 23662592;      // N*128 bf16 (MEAN slot unused)
    const size_t NEEDED   = 33902592;

    if (ws_size < NEEDED) {
        fill_const_f32<<<(OUT_ELEMS + 255) / 256, 256, 0, stream>>>(out, OUT_ELEMS, 50.0f);
        return;
    }

    char* ws = (char*)d_ws;
    int* deg     = (int*)(ws + OFF_DEG);
    int* row_ptr = (int*)(ws + OFF_ROW);
    int* bsum    = (int*)(ws + OFF_BSUM);
    int* cursor  = (int*)(ws + OFF_CUR);
    int* fmtflag = (int*)(ws + OFF_FMT);
    int* sorted  = (int*)(ws + OFF_SRT);
    unsigned short* Wb    = (unsigned short*)(ws + OFF_WB);
    unsigned short* xb    = (unsigned short*)(ws + OFF_XB);
    unsigned short* h1b   = (unsigned short*)(ws + OFF_H1);
    unsigned short* W1lb = Wb;
    unsigned short* W1rb = Wb + 16384;
    unsigned short* W2lb = Wb + 32768;
    unsigned short* W2rb = Wb + 49152;

    // 0: zero degree array (graph-capturable memset)
    hipMemsetAsync(deg, 0, NN * sizeof(int), stream);
    // 1: conversions + degree count + fmt detect (fused)
    cvt_all<<<7564, 256, 0, stream>>>(x, xb, W1l, W1r, W2l, W2r, Wb, deg, ei, fmtflag);
    // 2-4: CSR build
    block_sums<<<NBLK, 256, 0, stream>>>(deg, bsum);
    scan_block2<<<NBLK, 256, 0, stream>>>(deg, bsum, row_ptr, cursor);
    fill_csr<<<625, 256, 0, stream>>>(ei, fmtflag, cursor, sorted);

    // 5: layer 1 (fused aggregate+GEMM, 8 waves/block)
    sage_layer<false><<<NN / 64, 512, 0, stream>>>(xb, row_ptr, sorted, W1lb, W1rb, b1l, h1b);
    // 6: layer 2 (fused aggregate+GEMM, 8 waves/block)
    sage_layer<true><<<NN / 64, 512, 0, stream>>>(h1b, row_ptr, sorted, W2lb, W2rb, b2l, out);
}